// Round 4
// baseline (212.500 us; speedup 1.0000x reference)
//
#include <hip/hip_runtime.h>
#include <math.h>

#define TT 4096
#define DM 1024
#define BB 4
#define BT (BB * TT)
#define SENTINEL 0x7fffffff

#define NBLK 1024
#define BAR_OFF 458816   // barrier state in ws (3 instances x 256 B), memset to 0

// ws layout (bytes):
//   Q    : float[BT*2]  @ 0        (131072)
//   K    : float[BT*2]  @ 131072   (131072)  (interleaved k0,k1 pairs)
//   idx  : int[BT]      @ 262144   (65536)
//   rep  : int[BT]      @ 327680   (65536)
//   list : int[BT]      @ 393216   (65536)
//   cnt  : int          @ 458752   (4)
//   bar  : int[192]     @ 458816   (768)   3 x {cnt0[32], cnt1, gen, pad}

__device__ __forceinline__ float dot4(const float4 a, const float4 b) {
    return a.x * b.x + a.y * b.y + a.z * b.z + a.w * b.w;
}

// Two-level grid barrier: 32 groups of 32 blocks -> root -> generation flag.
// Device-scope atomics + __threadfence release/acquire. Each phase uses its
// own zero-initialized instance (no generation reuse).
__device__ __forceinline__ void grid_barrier(int* bar_inst) {
    __syncthreads();
    if (threadIdx.x == 0) {
        int* cnt0 = bar_inst;            // [32]
        int* cnt1 = bar_inst + 32;
        int* gen  = bar_inst + 33;
        const int g = (int)(blockIdx.x >> 5);   // 32 groups of 32
        __threadfence();                         // release prior writes (device)
        const int old_gen = __hip_atomic_load(gen, __ATOMIC_RELAXED, __HIP_MEMORY_SCOPE_AGENT);
        const int a = __hip_atomic_fetch_add(&cnt0[g], 1, __ATOMIC_ACQ_REL, __HIP_MEMORY_SCOPE_AGENT);
        if (a == 31) {
            const int r = __hip_atomic_fetch_add(cnt1, 1, __ATOMIC_ACQ_REL, __HIP_MEMORY_SCOPE_AGENT);
            if (r == 31) {
                __hip_atomic_fetch_add(gen, 1, __ATOMIC_ACQ_REL, __HIP_MEMORY_SCOPE_AGENT);
            } else {
                while (__hip_atomic_load(gen, __ATOMIC_RELAXED, __HIP_MEMORY_SCOPE_AGENT) == old_gen)
                    __builtin_amdgcn_s_sleep(8);
            }
        } else {
            while (__hip_atomic_load(gen, __ATOMIC_RELAXED, __HIP_MEMORY_SCOPE_AGENT) == old_gen)
                __builtin_amdgcn_s_sleep(8);
        }
        __threadfence();                         // acquire remote writes
    }
    __syncthreads();
}

// ============================================================================
// Persistent kernel: all 4 phases, 3 lightweight barriers. 1024 blocks x 256.
// ============================================================================
__global__ __launch_bounds__(256, 4) void persistent_kernel(
    const float* __restrict__ x, const float* __restrict__ wq,
    const float* __restrict__ wk, const float* __restrict__ wv,
    float* __restrict__ Q, float* __restrict__ K,
    int* __restrict__ idx, int* __restrict__ rep,
    int* __restrict__ list, int* __restrict__ cnt,
    int* __restrict__ bar, float* __restrict__ out)
{
    __shared__ union {
        float4 w[4][256];   // 16 KB, phase 0
        float2 ks[TT];      // 32 KB, phase 1
    } sm;

    const int tid  = threadIdx.x;
    const int bid  = blockIdx.x;
    const int wave = tid >> 6, lane = tid & 63;

    // ---------------- phase 0: Q,K projection + init rep/cnt ----------------
    sm.w[0][tid] = ((const float4*)(wq))[tid];
    sm.w[1][tid] = ((const float4*)(wq + DM))[tid];
    sm.w[2][tid] = ((const float4*)(wk))[tid];
    sm.w[3][tid] = ((const float4*)(wk + DM))[tid];
    for (int i = bid * 256 + tid; i < BT; i += NBLK * 256) rep[i] = SENTINEL;
    if (bid == 0 && tid == 0) cnt[0] = 0;
    __syncthreads();

    for (int vb = bid; vb < BT / 8; vb += NBLK) {
        const int row0 = vb * 8;
        #pragma unroll
        for (int gg = 0; gg < 2; ++gg) {
            const int row = row0 + gg * 4 + wave;
            const float4* xr = (const float4*)(x + (size_t)row * DM);
            float s0 = 0.f, s1 = 0.f, s2 = 0.f, s3 = 0.f;
            #pragma unroll
            for (int j = 0; j < 4; ++j) {
                const float4 xv = xr[j * 64 + lane];
                s0 += dot4(xv, sm.w[0][j * 64 + lane]);
                s1 += dot4(xv, sm.w[1][j * 64 + lane]);
                s2 += dot4(xv, sm.w[2][j * 64 + lane]);
                s3 += dot4(xv, sm.w[3][j * 64 + lane]);
            }
            #pragma unroll
            for (int off = 32; off > 0; off >>= 1) {
                s0 += __shfl_down(s0, off);
                s1 += __shfl_down(s1, off);
                s2 += __shfl_down(s2, off);
                s3 += __shfl_down(s3, off);
            }
            if (lane == 0) {
                ((float2*)Q)[row] = make_float2(s0, s1);
                ((float2*)K)[row] = make_float2(s2, s3);
            }
        }
    }

    grid_barrier(bar);

    // ---------------- phase 1: causal argmax, paired tiles (j, 1023-j) ------
    for (int pi = bid; pi < BB * 512; pi += NBLK) {
        const int b = pi >> 9;
        const int j = pi & 511;               // pair: tg = 1023-j (big), j (small)
        __syncthreads();                       // LDS readers of previous pair done
        const int nfill4 = (((1023 - j) * 4 + 4) >> 1);
        const float4* kb4 = (const float4*)(K + (size_t)b * TT * 2);
        float4* ks4 = (float4*)sm.ks;
        for (int i = tid; i < nfill4; i += 256) ks4[i] = kb4[i];
        __syncthreads();

        const float4* kp = (const float4*)sm.ks;   // pair p -> points 2p, 2p+1
        #pragma unroll
        for (int u = 0; u < 2; ++u) {
            const int tg = u ? j : (1023 - j);
            const int t = tg * 4 + wave;
            const float2 q = ((const float2*)Q)[b * TT + t];

            float best = -INFINITY;
            int bi = SENTINEL;
            int p = lane;
            while (2 * (p + 64) + 1 <= t) {
                const float4 a = kp[p];
                const float4 c = kp[p + 64];
                const float c0 = q.x * a.x + q.y * a.y;
                const float c1 = q.x * a.z + q.y * a.w;
                const float c2 = q.x * c.x + q.y * c.y;
                const float c3 = q.x * c.z + q.y * c.w;
                if (c0 > best) { best = c0; bi = 2 * p; }
                if (c1 > best) { best = c1; bi = 2 * p + 1; }
                if (c2 > best) { best = c2; bi = 2 * (p + 64); }
                if (c3 > best) { best = c3; bi = 2 * (p + 64) + 1; }
                p += 128;
            }
            while (2 * p <= t) {
                const float4 a = kp[p];
                const float c0 = q.x * a.x + q.y * a.y;
                if (c0 > best) { best = c0; bi = 2 * p; }
                if (2 * p + 1 <= t) {
                    const float c1 = q.x * a.z + q.y * a.w;
                    if (c1 > best) { best = c1; bi = 2 * p + 1; }
                }
                p += 64;
            }
            #pragma unroll
            for (int off = 32; off > 0; off >>= 1) {
                const float ov = __shfl_down(best, off);
                const int   oi = __shfl_down(bi, off);
                if (ov > best || (ov == best && oi < bi)) { best = ov; bi = oi; }
            }
            if (lane == 0) {
                idx[b * TT + t] = bi;
                const int old = atomicMin(&rep[b * TT + bi], t);
                if (old == SENTINEL) {
                    const int pp = atomicAdd(cnt, 1);
                    list[pp] = b * TT + bi;
                }
            }
        }
    }

    grid_barrier(bar + 64);

    // ---------------- phase 2: V rows for unique sources --------------------
    const int n = cnt[0];
    {
        const int slice = bid >> 4;            // 1024 blocks == exactly one pass
        const int usub  = bid & 15;
        const int e0 = slice * 16 + wave * 4;
        float4 w[4][4];
        #pragma unroll
        for (int r = 0; r < 4; ++r) {
            const float4* wr = (const float4*)(wv + (size_t)(e0 + r) * DM);
            #pragma unroll
            for (int j = 0; j < 4; ++j) w[r][j] = wr[j * 64 + lane];
        }
        for (int li = usub; li < n; li += 16) {
            const int bs = list[li];
            const int b  = bs >> 12;
            const int r  = rep[bs];
            const float4* xr = (const float4*)(x + (size_t)bs * DM);
            float4 xv[4];
            #pragma unroll
            for (int j = 0; j < 4; ++j) xv[j] = xr[j * 64 + lane];
            float s0 = 0.f, s1 = 0.f, s2 = 0.f, s3 = 0.f;
            #pragma unroll
            for (int j = 0; j < 4; ++j) {
                s0 += dot4(w[0][j], xv[j]);
                s1 += dot4(w[1][j], xv[j]);
                s2 += dot4(w[2][j], xv[j]);
                s3 += dot4(w[3][j], xv[j]);
            }
            #pragma unroll
            for (int off = 32; off > 0; off >>= 1) {
                s0 += __shfl_down(s0, off);
                s1 += __shfl_down(s1, off);
                s2 += __shfl_down(s2, off);
                s3 += __shfl_down(s3, off);
            }
            if (lane == 0)
                *(float4*)(out + ((size_t)(b * TT + r)) * DM + e0) = make_float4(s0, s1, s2, s3);
        }
    }

    grid_barrier(bar + 128);

    // ---------------- phase 3: broadcast representative rows ----------------
    for (int g4 = bid; g4 < BT / 4; g4 += NBLK) {
        const int bt = g4 * 4 + wave;
        const int b = bt >> 12, t = bt & (TT - 1);
        const int s = idx[bt];
        const int r = rep[b * TT + s];
        if (r == t) continue;                  // wave-uniform
        const float4* src = (const float4*)(out + ((size_t)(b * TT + r)) * DM);
        float4* dst = (float4*)(out + (size_t)bt * DM);
        #pragma unroll
        for (int k = 0; k < 4; ++k) dst[k * 64 + lane] = src[k * 64 + lane];
    }
}

// ============================================================================
// Fallback: verified 4-kernel chain (round-3 version).
// ============================================================================
__global__ __launch_bounds__(256) void qk_kernel(const float* __restrict__ x,
                                                 const float* __restrict__ wq,
                                                 const float* __restrict__ wk,
                                                 float* __restrict__ Q,
                                                 float* __restrict__ K,
                                                 int* __restrict__ rep,
                                                 int* __restrict__ cnt) {
    __shared__ float4 ws[4][256];
    const int tid = threadIdx.x;
    const int row0 = blockIdx.x * 8;

    ws[0][tid] = ((const float4*)(wq))[tid];
    ws[1][tid] = ((const float4*)(wq + DM))[tid];
    ws[2][tid] = ((const float4*)(wk))[tid];
    ws[3][tid] = ((const float4*)(wk + DM))[tid];

    if (tid < 8) rep[row0 + tid] = SENTINEL;
    if (blockIdx.x == 0 && tid == 8) cnt[0] = 0;
    __syncthreads();

    const int wave = tid >> 6, lane = tid & 63;
    #pragma unroll
    for (int g = 0; g < 2; ++g) {
        const int row = row0 + g * 4 + wave;
        const float4* xr = (const float4*)(x + (size_t)row * DM);
        float s0 = 0.f, s1 = 0.f, s2 = 0.f, s3 = 0.f;
        #pragma unroll
        for (int j = 0; j < 4; ++j) {
            const float4 xv = xr[j * 64 + lane];
            s0 += dot4(xv, ws[0][j * 64 + lane]);
            s1 += dot4(xv, ws[1][j * 64 + lane]);
            s2 += dot4(xv, ws[2][j * 64 + lane]);
            s3 += dot4(xv, ws[3][j * 64 + lane]);
        }
        #pragma unroll
        for (int off = 32; off > 0; off >>= 1) {
            s0 += __shfl_down(s0, off);
            s1 += __shfl_down(s1, off);
            s2 += __shfl_down(s2, off);
            s3 += __shfl_down(s3, off);
        }
        if (lane == 0) {
            ((float2*)Q)[row] = make_float2(s0, s1);
            ((float2*)K)[row] = make_float2(s2, s3);
        }
    }
}

__global__ __launch_bounds__(256) void argmax_kernel(const float* __restrict__ Q,
                                                     const float* __restrict__ K,
                                                     int* __restrict__ idx,
                                                     int* __restrict__ rep,
                                                     int* __restrict__ list,
                                                     int* __restrict__ cnt) {
    __shared__ float2 ks[TT];
    const int b = blockIdx.x >> 9;
    const int j = blockIdx.x & 511;
    const int tid = threadIdx.x;

    const int nfill4 = (((1023 - j) * 4 + 4) >> 1);
    const float4* kb4 = (const float4*)(K + (size_t)b * TT * 2);
    float4* ks4 = (float4*)ks;
    for (int i = tid; i < nfill4; i += 256) ks4[i] = kb4[i];
    __syncthreads();

    const int wave = tid >> 6, lane = tid & 63;
    const float4* kp = (const float4*)ks;

    #pragma unroll
    for (int u = 0; u < 2; ++u) {
        const int tg = u ? j : (1023 - j);
        const int t = tg * 4 + wave;
        const float2 q = ((const float2*)Q)[b * TT + t];

        float best = -INFINITY;
        int bi = SENTINEL;
        int p = lane;
        while (2 * (p + 64) + 1 <= t) {
            const float4 a = kp[p];
            const float4 c = kp[p + 64];
            const float c0 = q.x * a.x + q.y * a.y;
            const float c1 = q.x * a.z + q.y * a.w;
            const float c2 = q.x * c.x + q.y * c.y;
            const float c3 = q.x * c.z + q.y * c.w;
            if (c0 > best) { best = c0; bi = 2 * p; }
            if (c1 > best) { best = c1; bi = 2 * p + 1; }
            if (c2 > best) { best = c2; bi = 2 * (p + 64); }
            if (c3 > best) { best = c3; bi = 2 * (p + 64) + 1; }
            p += 128;
        }
        while (2 * p <= t) {
            const float4 a = kp[p];
            const float c0 = q.x * a.x + q.y * a.y;
            if (c0 > best) { best = c0; bi = 2 * p; }
            if (2 * p + 1 <= t) {
                const float c1 = q.x * a.z + q.y * a.w;
                if (c1 > best) { best = c1; bi = 2 * p + 1; }
            }
            p += 64;
        }
        #pragma unroll
        for (int off = 32; off > 0; off >>= 1) {
            const float ov = __shfl_down(best, off);
            const int   oi = __shfl_down(bi, off);
            if (ov > best || (ov == best && oi < bi)) { best = ov; bi = oi; }
        }
        if (lane == 0) {
            idx[b * TT + t] = bi;
            const int old = atomicMin(&rep[b * TT + bi], t);
            if (old == SENTINEL) {
                const int pp = atomicAdd(cnt, 1);
                list[pp] = b * TT + bi;
            }
        }
    }
}

__global__ __launch_bounds__(256) void vrow_kernel(const float* __restrict__ x,
                                                   const float* __restrict__ wv,
                                                   const int* __restrict__ rep,
                                                   const int* __restrict__ list,
                                                   const int* __restrict__ cnt,
                                                   float* __restrict__ out) {
    const int tid = threadIdx.x, wave = tid >> 6, lane = tid & 63;
    const int slice = blockIdx.x >> 4;
    const int usub  = blockIdx.x & 15;
    const int e0 = slice * 16 + wave * 4;

    float4 w[4][4];
    #pragma unroll
    for (int r = 0; r < 4; ++r) {
        const float4* wr = (const float4*)(wv + (size_t)(e0 + r) * DM);
        #pragma unroll
        for (int j = 0; j < 4; ++j) w[r][j] = wr[j * 64 + lane];
    }

    const int n = cnt[0];
    for (int li = usub; li < n; li += 16) {
        const int bs = list[li];
        const int b  = bs >> 12;
        const int r  = rep[bs];
        const float4* xr = (const float4*)(x + (size_t)bs * DM);
        float4 xv[4];
        #pragma unroll
        for (int j = 0; j < 4; ++j) xv[j] = xr[j * 64 + lane];

        float s0 = 0.f, s1 = 0.f, s2 = 0.f, s3 = 0.f;
        #pragma unroll
        for (int j = 0; j < 4; ++j) {
            s0 += dot4(w[0][j], xv[j]);
            s1 += dot4(w[1][j], xv[j]);
            s2 += dot4(w[2][j], xv[j]);
            s3 += dot4(w[3][j], xv[j]);
        }
        #pragma unroll
        for (int off = 32; off > 0; off >>= 1) {
            s0 += __shfl_down(s0, off);
            s1 += __shfl_down(s1, off);
            s2 += __shfl_down(s2, off);
            s3 += __shfl_down(s3, off);
        }
        if (lane == 0)
            *(float4*)(out + ((size_t)(b * TT + r)) * DM + e0) = make_float4(s0, s1, s2, s3);
    }
}

__global__ __launch_bounds__(256) void gather_kernel(const int* __restrict__ idx,
                                                     const int* __restrict__ rep,
                                                     float* __restrict__ out) {
    const int tid = threadIdx.x, wave = tid >> 6, lane = tid & 63;
    const int bt = blockIdx.x * 4 + wave;
    const int b = bt >> 12, t = bt & (TT - 1);
    const int s = idx[bt];
    const int r = rep[b * TT + s];
    if (r == t) return;
    const float4* src = (const float4*)(out + ((size_t)(b * TT + r)) * DM);
    float4* dst = (float4*)(out + (size_t)bt * DM);
    #pragma unroll
    for (int k = 0; k < 4; ++k) dst[k * 64 + lane] = src[k * 64 + lane];
}

extern "C" void kernel_launch(void* const* d_in, const int* in_sizes, int n_in,
                              void* d_out, int out_size, void* d_ws, size_t ws_size,
                              hipStream_t stream) {
    const float* x  = (const float*)d_in[0];
    const float* wq = (const float*)d_in[1];
    const float* wk = (const float*)d_in[2];
    const float* wv = (const float*)d_in[3];
    float* out = (float*)d_out;

    char* ws = (char*)d_ws;
    float* Q    = (float*)(ws);
    float* K    = (float*)(ws + 131072);
    int*   idx  = (int*)  (ws + 262144);
    int*   rep  = (int*)  (ws + 327680);
    int*   list = (int*)  (ws + 393216);
    int*   cnt  = (int*)  (ws + 458752);
    int*   bar  = (int*)  (ws + BAR_OFF);

    // Persistent path requires all 1024 blocks co-resident (>=4 blocks/CU).
    static int mode = 0;   // 0 = untested, 1 = persistent, -1 = fallback
    if (mode == 0) {
        int occ = 0;
        if (hipOccupancyMaxActiveBlocksPerMultiprocessor(
                &occ, (const void*)persistent_kernel, 256, 0) == hipSuccess && occ >= 4)
            mode = 1;
        else
            mode = -1;
    }

    if (mode == 1) {
        hipMemsetAsync(ws + BAR_OFF, 0, 768, stream);   // zero barrier state
        persistent_kernel<<<NBLK, 256, 0, stream>>>(x, wq, wk, wv, Q, K,
                                                    idx, rep, list, cnt, bar, out);
    } else {
        qk_kernel<<<BT / 8, 256, 0, stream>>>(x, wq, wk, Q, K, rep, cnt);
        argmax_kernel<<<BB * 512, 256, 0, stream>>>(Q, K, idx, rep, list, cnt);
        vrow_kernel<<<1024, 256, 0, stream>>>(x, wv, rep, list, cnt, out);
        gather_kernel<<<BT / 4, 256, 0, stream>>>(idx, rep, out);
    }
}